// Round 16
// baseline (30.697 us; speedup 1.0000x reference)
//
#include <hip/hip_runtime.h>

// Problem constants (match reference setup_inputs)
#define B_ 8
#define T_ 1024
#define S_ 4096
#define H_ 256

#define STRIP 64           // K2 strip granularity (unchanged)
#define BSTRIP 128         // tokens per K1 block (64 lanes x 2 via float2)
#define CHUNK 128          // tag rows per early-exit check (8 waves x 16 rows)

// K1: top-down early-exit column-max, float2-widened (one change vs R12).
// Cross-round data: scalar-load adaptive K1 delivers ~4.2 TB/s (issue-rate
// capped at 256B/wave-request); R6's float2 full-scan hit ~6 TB/s. This keeps
// the early exit but restores the 512B/request width: 256 blocks x 512
// threads (8 waves/CU); lane owns TWO token columns; wave w owns 16 rows of
// each 128-row chunk. Exit via per-token dual ballots (OR across waves = found
// by any wave; AND of the two token masks = all 128 tokens found).
// Epilogue writes L (threads 0..127) and TWO 64-token [Lmin,Lmax] range
// entries so K2 stays byte-identical to the proven R12 form.
__global__ void __launch_bounds__(512) colmax_f2_kernel(const float* __restrict__ ttt,
                                                        int* __restrict__ L,
                                                        int2* __restrict__ range) {
    __shared__ unsigned long long wm0[2][8], wm1[2][8];
    __shared__ int red[8][BSTRIP];
    const int strippos = blockIdx.x >> 3;   // 0..31 (128-token strips)
    const int b  = blockIdx.x & 7;
    const int s0 = strippos * BSTRIP;
    const int w    = threadIdx.x >> 6;      // 0..7
    const int lane = threadIdx.x & 63;

    const float* colbase = ttt + (size_t)b * T_ * S_ + s0 + lane * 2;

    int best0 = -1, best1 = -1;             // lane's two token columns
    int par = 0;
    float2 v[16], vn[16];

    // prologue: top chunk (rows T-CHUNK .. T-1), wave w's 16-row slice
    {
        const float* p = colbase + (size_t)(T_ - CHUNK + w * 16) * S_;
#pragma unroll
        for (int j = 0; j < 16; ++j)
            v[j] = *reinterpret_cast<const float2*>(p + (size_t)j * S_);
    }

    for (int thi = T_; thi > 0; thi -= CHUNK) {
        const int t0 = thi - CHUNK + w * 16;
        if (thi > CHUNK) {                  // prefetch next chunk
            const float* pn = colbase + (size_t)(t0 - CHUNK) * S_;
#pragma unroll
            for (int j = 0; j < 16; ++j)
                vn[j] = *reinterpret_cast<const float2*>(pn + (size_t)j * S_);
        }
        int lm0 = -1, lm1 = -1;
#pragma unroll
        for (int j = 0; j < 16; ++j) {      // ascending j -> in-chunk max
            if (v[j].x > 0.0f) lm0 = t0 + j;
            if (v[j].y > 0.0f) lm1 = t0 + j;
        }
        best0 = max(best0, lm0);
        best1 = max(best1, lm1);

        wm0[par][w] = __ballot(best0 >= 0);
        wm1[par][w] = __ballot(best1 >= 0);
        __syncthreads();
        unsigned long long a0 = wm0[par][0] | wm0[par][1] | wm0[par][2] | wm0[par][3]
                              | wm0[par][4] | wm0[par][5] | wm0[par][6] | wm0[par][7];
        unsigned long long a1 = wm1[par][0] | wm1[par][1] | wm1[par][2] | wm1[par][3]
                              | wm1[par][4] | wm1[par][5] | wm1[par][6] | wm1[par][7];
        if ((a0 & a1) == ~0ull) break;      // all 128 tokens found
        par ^= 1;
#pragma unroll
        for (int j = 0; j < 16; ++j)
            v[j] = vn[j];
    }

    // epilogue: cross-wave max-combine -> L; two 64-token ranges
    red[w][lane * 2]     = best0;           // token index within strip
    red[w][lane * 2 + 1] = best1;
    __syncthreads();
    if (threadIdx.x < BSTRIP) {             // waves 0,1; thread = token
        const int tid = threadIdx.x;        // wave h handles tokens h*64..h*64+63
        int m = red[0][tid];
#pragma unroll
        for (int k = 1; k < 8; ++k) m = max(m, red[k][tid]);
        L[b * S_ + s0 + tid] = m;

        int mn = (m < 0) ? 0x7fffffff : m;  // not-found -> +INF for min
        int mx = m;                         // not-found -1 never wins max
#pragma unroll
        for (int k = 32; k >= 1; k >>= 1) {
            mn = min(mn, __shfl_xor(mn, k));
            mx = max(mx, __shfl_xor(mx, k));
        }
        if (lane == 0) {                    // one entry per 64-token half
            int2 rg = {mn, mx};             // empty -> (INT_MAX,-1): no match
            range[b * (S_ / STRIP) + strippos * 2 + w] = rg;
        }
    }
}

// K2: range-filtered gather + mean + seq_emb (unchanged from R12, absmax 0.0).
__global__ void __launch_bounds__(256) gather_range_kernel(const float* __restrict__ inputs,
                                                           const int* __restrict__ L,
                                                           const int2* __restrict__ range,
                                                           const float* __restrict__ seq_emb,
                                                           float* __restrict__ out) {
    const int wid  = threadIdx.x >> 6;
    const int lane = threadIdx.x & 63;
    const int bt = blockIdx.x * 4 + wid;         // (b*T + t), 4 waves per block
    const int b = bt >> 10;
    const int t = bt & (T_ - 1);

    const float4* in4 = reinterpret_cast<const float4*>(inputs);

    int2 rg = range[b * (S_ / STRIP) + lane];    // lane = strip id (64 strips)
    unsigned long long smask = __ballot(rg.x <= t && t <= rg.y);

    float4 acc = {0.0f, 0.0f, 0.0f, 0.0f};
    int c = 0;

    while (smask) {                              // wave-uniform loop
        int strip = __ffsll(smask) - 1; smask &= smask - 1;
        int Lv = L[b * S_ + strip * STRIP + lane];
        unsigned long long bm = __ballot(Lv == t);
        while (bm) {
            int l = __ffsll(bm) - 1; bm &= bm - 1;
            int s = strip * STRIP + l;
            float4 r = in4[(size_t)(b * S_ + s) * (H_ / 4) + lane];
            acc.x += r.x; acc.y += r.y; acc.z += r.z; acc.w += r.w; c++;
        }
    }

    float inv = (c > 0) ? (1.0f / (float)c) : 0.0f;   // empty row -> just emb
    float4 e = reinterpret_cast<const float4*>(seq_emb)[t * (H_ / 4) + lane];
    float4 o;
    o.x = acc.x * inv + e.x;
    o.y = acc.y * inv + e.y;
    o.z = acc.z * inv + e.z;
    o.w = acc.w * inv + e.w;
    reinterpret_cast<float4*>(out)[(size_t)bt * (H_ / 4) + lane] = o;
}

extern "C" void kernel_launch(void* const* d_in, const int* in_sizes, int n_in,
                              void* d_out, int out_size, void* d_ws, size_t ws_size,
                              hipStream_t stream) {
    const float* inputs  = (const float*)d_in[0];   // [B,S,H]
    const float* ttt     = (const float*)d_in[1];   // [B,T,S]
    const float* seq_emb = (const float*)d_in[2];   // [T,H]
    float* out = (float*)d_out;                     // [B,T,H]

    int* L = (int*)d_ws;                            // B*S ints (128 KiB)
    int2* range = (int2*)(L + B_ * S_);             // 512 int2 (4 KiB)

    // K1: float2-widened early-exit column-max (256 blocks x 8 waves)
    colmax_f2_kernel<<<B_ * (S_ / BSTRIP), 512, 0, stream>>>(ttt, L, range);

    // K2: range-filtered gather + mean + emb (B*T/4 blocks, 1 wave per row)
    gather_range_kernel<<<B_ * T_ / 4, 256, 0, stream>>>(inputs, L, range, seq_emb, out);
}

// Round 17
// 28.572 us; speedup vs baseline: 1.0744x; 1.0744x over previous
//
#include <hip/hip_runtime.h>

// Problem constants (match reference setup_inputs)
#define B_ 8
#define T_ 1024
#define S_ 4096
#define H_ 256

#define STRIP 64           // tokens per K1 block
#define CHUNK 128          // tag rows per early-exit check (4 waves x 32 rows)

// K1: top-down early-exit column-max, software-pipelined, + free epilogue
// emitting per-strip [Lmin,Lmax] ranges for K2's strip filter.
// SESSION JOURNAL (final): K1 lands at ~18-22us under ALL tested structures
// (full-scan R6, early-exit R7, cost-paired R10, pipelined R11, reg-dbuf R13,
// float2-widened R16); fusion via grid.sync (R5) or flag-handoff (R14)
// regresses >=2x; K2 is ~2.5us. 28.3us total = practical floor: adaptive
// mask scan is L3-latency/issue-bound (~4.2 TB/s effective), and the ~4us of
// launch-boundary cost is cheaper than any on-device barrier this chip offers.
__global__ void __launch_bounds__(256) colmax_pipe_kernel(const float* __restrict__ ttt,
                                                          int* __restrict__ L,
                                                          int2* __restrict__ range) {
    __shared__ unsigned long long wmask[2][4];
    __shared__ int red[4][STRIP];
    const int strippos = blockIdx.x >> 3;   // low s0 (expensive) first
    const int b  = blockIdx.x & 7;
    const int s0 = strippos * STRIP;
    const int w    = threadIdx.x >> 6;
    const int lane = threadIdx.x & 63;

    const float* colbase = ttt + (size_t)b * T_ * S_ + s0 + lane;

    int best = -1;
    int par = 0;
    float v[32], vn[32];

    // prologue: load top chunk (rows T-CHUNK .. T-1), wave w's 32-row slice
    {
        const float* p = colbase + (size_t)(T_ - CHUNK + w * 32) * S_;
#pragma unroll
        for (int j = 0; j < 32; ++j)
            v[j] = p[(size_t)j * S_];
    }

    for (int thi = T_; thi > 0; thi -= CHUNK) {
        const int t0 = thi - CHUNK + w * 32;
        // prefetch next chunk while current is processed
        if (thi > CHUNK) {
            const float* pn = colbase + (size_t)(t0 - CHUNK) * S_;
#pragma unroll
            for (int j = 0; j < 32; ++j)
                vn[j] = pn[(size_t)j * S_];
        }
        // process current chunk (ascending j -> in-chunk max; chunks visited
        // top-down so first-found is the global max for this lane)
        int lm = -1;
#pragma unroll
        for (int j = 0; j < 32; ++j)
            if (v[j] > 0.0f) lm = t0 + j;
        best = max(best, lm);

        wmask[par][w] = __ballot(best >= 0);    // all lanes write same value
        __syncthreads();
        unsigned long long all = wmask[par][0] | wmask[par][1]
                               | wmask[par][2] | wmask[par][3];
        if (all == ~0ull) break;                // uniform across block
        par ^= 1;
#pragma unroll
        for (int j = 0; j < 32; ++j)
            v[j] = vn[j];
    }

    // epilogue: cross-wave max-combine -> L, plus strip [Lmin,Lmax] -> range
    red[w][lane] = best;
    __syncthreads();
    if (threadIdx.x < STRIP) {                  // exactly wave 0, all 64 lanes
        const int tid = threadIdx.x;
        int m = max(max(red[0][tid], red[1][tid]),
                    max(red[2][tid], red[3][tid]));
        L[b * S_ + s0 + tid] = m;
        int mn = (m < 0) ? 0x7fffffff : m;      // not-found -> +INF for min
        int mx = m;                             // not-found -1 never wins max
#pragma unroll
        for (int k = 32; k >= 1; k >>= 1) {
            mn = min(mn, __shfl_xor(mn, k));
            mx = max(mx, __shfl_xor(mx, k));
        }
        if (tid == 0) {
            int2 rg = {mn, mx};                 // empty strip -> (INT_MAX,-1): no t matches
            range[b * (S_ / STRIP) + strippos] = rg;
        }
    }
}

// K2: range-filtered gather + mean + seq_emb. One wave per (b,t) output row.
// Lane = strip: one ballot over per-strip [Lmin,Lmax] selects candidate strips
// (L[b,s]==t implies t is within strip(s)'s range). Only those strips' 64 L
// values are read (coalesced 256B); matches gather coalesced float4 input
// rows. Ascending strip then ascending bit -> ascending s (absmax-0 order).
__global__ void __launch_bounds__(256) gather_range_kernel(const float* __restrict__ inputs,
                                                           const int* __restrict__ L,
                                                           const int2* __restrict__ range,
                                                           const float* __restrict__ seq_emb,
                                                           float* __restrict__ out) {
    const int wid  = threadIdx.x >> 6;
    const int lane = threadIdx.x & 63;
    const int bt = blockIdx.x * 4 + wid;         // (b*T + t), 4 waves per block
    const int b = bt >> 10;
    const int t = bt & (T_ - 1);

    const float4* in4 = reinterpret_cast<const float4*>(inputs);

    int2 rg = range[b * (S_ / STRIP) + lane];    // lane = strip id (64 strips)
    unsigned long long smask = __ballot(rg.x <= t && t <= rg.y);

    float4 acc = {0.0f, 0.0f, 0.0f, 0.0f};
    int c = 0;

    while (smask) {                              // wave-uniform loop
        int strip = __ffsll(smask) - 1; smask &= smask - 1;
        int Lv = L[b * S_ + strip * STRIP + lane];
        unsigned long long bm = __ballot(Lv == t);
        while (bm) {
            int l = __ffsll(bm) - 1; bm &= bm - 1;
            int s = strip * STRIP + l;
            float4 r = in4[(size_t)(b * S_ + s) * (H_ / 4) + lane];
            acc.x += r.x; acc.y += r.y; acc.z += r.z; acc.w += r.w; c++;
        }
    }

    float inv = (c > 0) ? (1.0f / (float)c) : 0.0f;   // empty row -> just emb
    float4 e = reinterpret_cast<const float4*>(seq_emb)[t * (H_ / 4) + lane];
    float4 o;
    o.x = acc.x * inv + e.x;
    o.y = acc.y * inv + e.y;
    o.z = acc.z * inv + e.z;
    o.w = acc.w * inv + e.w;
    reinterpret_cast<float4*>(out)[(size_t)bt * (H_ / 4) + lane] = o;
}

extern "C" void kernel_launch(void* const* d_in, const int* in_sizes, int n_in,
                              void* d_out, int out_size, void* d_ws, size_t ws_size,
                              hipStream_t stream) {
    const float* inputs  = (const float*)d_in[0];   // [B,S,H]
    const float* ttt     = (const float*)d_in[1];   // [B,T,S]
    const float* seq_emb = (const float*)d_in[2];   // [T,H]
    float* out = (float*)d_out;                     // [B,T,H]

    int* L = (int*)d_ws;                            // B*S ints (128 KiB)
    int2* range = (int2*)(L + B_ * S_);             // 512 int2 (4 KiB)

    // K1: software-pipelined early-exit column-max + strip ranges
    colmax_pipe_kernel<<<B_ * (S_ / STRIP), 256, 0, stream>>>(ttt, L, range);

    // K2: range-filtered gather + mean + emb (B*T/4 blocks, 1 wave per row)
    gather_range_kernel<<<B_ * T_ / 4, 256, 0, stream>>>(inputs, L, range, seq_emb, out);
}